// Round 5
// baseline (446.043 us; speedup 1.0000x reference)
//
#include <hip/hip_runtime.h>

// Problem constants
#define NB 2
#define NN 160
#define NPAIR (NN*NN)          // 25600
#define OUT_PAIRS_OFF 307200   // 3 * NB*NPAIR*2 fp32 elements before emb_pairs

// ---------------------------------------------------------------------------
// Kernel 1: factorized projections (fp32 VALU GEMM):
//   proj[(t*2+s)*320 + p][f] = sum_{c<768} emb[p][c] * W1_t[s*768+c][f] (+b1)
// M=320, N=3072 (t,s,f), K=768. 64x64 tile/block, 16x16 threads, 4x4 micro.
// ---------------------------------------------------------------------------
__global__ __launch_bounds__(256) void proj_fp32_kernel(
    const float* __restrict__ geo, const float* __restrict__ app,
    const float* __restrict__ con,
    const float* __restrict__ w1c, const float* __restrict__ w1r,
    const float* __restrict__ w1l,
    const float* __restrict__ b1c, const float* __restrict__ b1r,
    const float* __restrict__ b1l,
    float* __restrict__ proj)
{
    __shared__ float As[64][17];
    __shared__ float Bs[16][68];

    const int tid = threadIdx.x;
    const int m0 = blockIdx.x * 64;
    const int n0 = blockIdx.y * 64;
    const int t  = n0 >> 10;
    const int s  = (n0 >> 9) & 1;
    const int f0 = n0 & 511;

    const float* w1 = (t == 0) ? w1c : ((t == 1) ? w1r : w1l);
    const float* b1 = (t == 0) ? b1c : ((t == 1) ? b1r : b1l);

    const int ty = tid >> 4, tx = tid & 15;
    const int ar = tid >> 2, ac = (tid & 3) * 4;
    const int bk = tid >> 4, bn = (tid & 15) * 4;

    float acc[4][4] = {};

    for (int k0 = 0; k0 < 768; k0 += 16) {
        {
            const int c = k0 + ac;
            const int m = c >> 8, off = c & 255;
            const float* src = ((m == 0) ? geo : (m == 1) ? app : con)
                               + (size_t)(m0 + ar) * 256 + off;
            const float4 v = *(const float4*)src;
            As[ar][ac + 0] = v.x; As[ar][ac + 1] = v.y;
            As[ar][ac + 2] = v.z; As[ar][ac + 3] = v.w;
        }
        {
            const float4 v = *(const float4*)(
                w1 + (size_t)(s * 768 + k0 + bk) * 512 + f0 + bn);
            Bs[bk][bn + 0] = v.x; Bs[bk][bn + 1] = v.y;
            Bs[bk][bn + 2] = v.z; Bs[bk][bn + 3] = v.w;
        }
        __syncthreads();

        #pragma unroll
        for (int k = 0; k < 16; ++k) {
            const float4 b = *(const float4*)&Bs[k][tx * 4];
            const float a0 = As[ty * 4 + 0][k];
            const float a1 = As[ty * 4 + 1][k];
            const float a2 = As[ty * 4 + 2][k];
            const float a3 = As[ty * 4 + 3][k];
            acc[0][0] += a0 * b.x; acc[0][1] += a0 * b.y;
            acc[0][2] += a0 * b.z; acc[0][3] += a0 * b.w;
            acc[1][0] += a1 * b.x; acc[1][1] += a1 * b.y;
            acc[1][2] += a1 * b.z; acc[1][3] += a1 * b.w;
            acc[2][0] += a2 * b.x; acc[2][1] += a2 * b.y;
            acc[2][2] += a2 * b.z; acc[2][3] += a2 * b.w;
            acc[3][0] += a3 * b.x; acc[3][1] += a3 * b.y;
            acc[3][2] += a3 * b.z; acc[3][3] += a3 * b.w;
        }
        __syncthreads();
    }

    float4 bias = {0.f, 0.f, 0.f, 0.f};
    if (s == 0) bias = *(const float4*)&b1[f0 + tx * 4];

    #pragma unroll
    for (int r = 0; r < 4; ++r) {
        float4 o;
        o.x = acc[r][0] + bias.x; o.y = acc[r][1] + bias.y;
        o.z = acc[r][2] + bias.z; o.w = acc[r][3] + bias.w;
        *(float4*)&proj[(size_t)((t * 2 + s) * 320 + m0 + ty * 4 + r) * 512
                        + f0 + tx * 4] = o;
    }
}

// ---------------------------------------------------------------------------
// Kernel 2: per 8x8 pair tile: h = relu(P1[j]+P2[i]); logits = h@W2 + b2;
// softmax(k=2) -> float2 store (FP32 OUTPUT). 3 heads sequentially.
// ---------------------------------------------------------------------------
__global__ __launch_bounds__(64) void heads_kernel(
    const float* __restrict__ proj,
    const float* __restrict__ w2c, const float* __restrict__ b2c,
    const float* __restrict__ w2r, const float* __restrict__ b2r,
    const float* __restrict__ w2l, const float* __restrict__ b2l,
    float* __restrict__ out)
{
    __shared__ float P1s[8][516];
    __shared__ float P2s[8][516];
    __shared__ float w2s[1024];
    __shared__ float b2s[2];

    const int tid = threadIdx.x;
    const int bid = blockIdx.x;
    const int b   = bid / 400;
    const int rem = bid - b * 400;
    const int it  = rem / 20;
    const int jt  = rem - it * 20;
    const int i0 = it * 8, j0 = jt * 8;
    const int ii = tid >> 3, jj = tid & 7;

    #pragma unroll
    for (int t = 0; t < 3; ++t) {
        const float* w2 = (t == 0) ? w2c : ((t == 1) ? w2r : w2l);
        const float* b2 = (t == 0) ? b2c : ((t == 1) ? b2r : b2l);

        for (int u = tid; u < 2048; u += 64) {
            const int tile = u >> 10;
            const int r    = (u >> 7) & 7;
            const int f4   = u & 127;
            const int p    = b * 160 + (tile ? (i0 + r) : (j0 + r));
            const float4 v = *(const float4*)(
                proj + ((size_t)((t * 2 + tile) * 320 + p)) * 512 + f4 * 4);
            float* dst = tile ? &P2s[r][f4 * 4] : &P1s[r][f4 * 4];
            *(float4*)dst = v;
        }
        for (int u = tid; u < 256; u += 64)
            *(float4*)&w2s[u * 4] = *(const float4*)(w2 + u * 4);
        if (tid < 2) b2s[tid] = b2[tid];
        __syncthreads();

        float a0 = b2s[0], a1 = b2s[1];
        for (int f = 0; f < 512; f += 4) {
            const float4 p1 = *(const float4*)&P1s[jj][f];
            const float4 p2 = *(const float4*)&P2s[ii][f];
            const float4 wA = *(const float4*)&w2s[f * 2];      // f, f+1
            const float4 wB = *(const float4*)&w2s[f * 2 + 4];  // f+2, f+3
            const float h0 = fmaxf(p1.x + p2.x, 0.f);
            const float h1 = fmaxf(p1.y + p2.y, 0.f);
            const float h2 = fmaxf(p1.z + p2.z, 0.f);
            const float h3 = fmaxf(p1.w + p2.w, 0.f);
            a0 += h0 * wA.x + h1 * wA.z + h2 * wB.x + h3 * wB.z;
            a1 += h0 * wA.y + h1 * wA.w + h2 * wB.y + h3 * wB.w;
        }

        const float mx = fmaxf(a0, a1);
        const float e0 = __expf(a0 - mx);
        const float e1 = __expf(a1 - mx);
        const float rs = 1.f / (e0 + e1);

        const int pr = b * 25600 + (i0 + ii) * 160 + (j0 + jj);
        float2 o; o.x = e0 * rs; o.y = e1 * rs;
        ((float2*)out)[t * 51200 + pr] = o;
        __syncthreads();
    }
}

// ---------------------------------------------------------------------------
// Kernel 3: emb_pairs, FP32 passthrough (314.6 MB write — the roofline).
// Row (b, i*160+j) = [emb[b,j] (1536B x... 768 floats? no: 768 floats), emb[b,i]]
// 384 float4 chunks per row (192 per half; 64 per modality). Runs LAST —
// overwrites the proj scratch at the head of this region.
// ---------------------------------------------------------------------------
__global__ __launch_bounds__(256) void pairs_kernel(
    const float* __restrict__ geo, const float* __restrict__ app,
    const float* __restrict__ con,
    float4* __restrict__ outp)
{
    const int idx = blockIdx.x * 256 + threadIdx.x;   // exactly 19,660,800
    const int row = idx / 384;
    const int c   = idx - row * 384;
    const int b   = row / 25600;
    const int rem = row - b * 25600;
    const int i   = rem / 160;
    const int j   = rem - i * 160;

    int cc = c, pt = j;                 // first half = emb[b, j]
    if (c >= 192) { pt = i; cc = c - 192; }
    const int m   = cc >> 6;            // 64 chunks per modality (256 floats)
    const int off = cc & 63;
    const float* src = ((m == 0) ? geo : (m == 1) ? app : con)
                       + ((size_t)(b * 160 + pt)) * 256 + off * 4;

    outp[idx] = *(const float4*)src;
}

extern "C" void kernel_launch(void* const* d_in, const int* in_sizes, int n_in,
                              void* d_out, int out_size, void* d_ws, size_t ws_size,
                              hipStream_t stream)
{
    const float* geo = (const float*)d_in[0];
    const float* app = (const float*)d_in[1];
    const float* con = (const float*)d_in[2];
    const float* w1c = (const float*)d_in[3];
    const float* b1c = (const float*)d_in[4];
    const float* w2c = (const float*)d_in[5];
    const float* b2c = (const float*)d_in[6];
    const float* w1r = (const float*)d_in[7];
    const float* b1r = (const float*)d_in[8];
    const float* w2r = (const float*)d_in[9];
    const float* b2r = (const float*)d_in[10];
    const float* w1l = (const float*)d_in[11];
    const float* b1l = (const float*)d_in[12];
    const float* w2l = (const float*)d_in[13];
    const float* b2l = (const float*)d_in[14];

    float* out = (float*)d_out;

    // proj scratch (6*320*512 fp32 = 3.93 MB) at the head of the emb_pairs
    // region; pairs_kernel overwrites it LAST. No d_ws dependence.
    float* proj = out + OUT_PAIRS_OFF;

    // 1) factorized projections (GEMM 320 x 3072 x 768, fp32)
    proj_fp32_kernel<<<dim3(5, 48), 256, 0, stream>>>(
        geo, app, con, w1c, w1r, w1l, b1c, b1r, b1l, proj);

    // 2) pairwise heads: relu + W2 + softmax -> fp32 float2 per pair
    heads_kernel<<<800, 64, 0, stream>>>(
        proj, w2c, b2c, w2r, b2r, w2l, b2l, out);

    // 3) emb_pairs fp32 streaming write: 19,660,800 float4 chunks (314.6 MB)
    pairs_kernel<<<76800, 256, 0, stream>>>(
        geo, app, con, (float4*)(out + OUT_PAIRS_OFF));
}